// Round 1
// baseline (1466.108 us; speedup 1.0000x reference)
//
#include <hip/hip_runtime.h>
#include <hip/hip_bf16.h>

#define SEQN 4096
#define HD 64
#define TB 16
#define SB 64
#define CCH 512

// ---------------- GroupNorm stats: one block per group (32 groups, 65536 floats each)
__global__ __launch_bounds__(256) void gn_stats(const float* __restrict__ x,
                                                float* __restrict__ stats) {
    const int g = blockIdx.x;
    const float* xs = x + (size_t)g * 65536;
    const int tid = threadIdx.x;
    float s = 0.f, ss = 0.f;
    for (int i = tid; i < 65536 / 4; i += 256) {
        float4 v = ((const float4*)xs)[i];
        s  += v.x + v.y + v.z + v.w;
        ss += v.x * v.x + v.y * v.y + v.z * v.z + v.w * v.w;
    }
    // wave butterfly then cross-wave via LDS
    for (int off = 32; off; off >>= 1) {
        s  += __shfl_xor(s, off);
        ss += __shfl_xor(ss, off);
    }
    __shared__ float red[8];
    const int wave = tid >> 6;
    const int lane = tid & 63;
    if (lane == 0) { red[wave] = s; red[4 + wave] = ss; }
    __syncthreads();
    if (tid == 0) {
        float S  = red[0] + red[1] + red[2] + red[3];
        float SS = red[4] + red[5] + red[6] + red[7];
        float mean = S * (1.f / 65536.f);
        float var  = SS * (1.f / 65536.f) - mean * mean;
        stats[g]      = mean;
        stats[32 + g] = rsqrtf(var + 1e-5f);
    }
}

// ---------------- GroupNorm apply: xn = (x - mean) * rstd * w + b
__global__ __launch_bounds__(256) void gn_apply(const float* __restrict__ x,
                                                const float* __restrict__ stats,
                                                const float* __restrict__ w,
                                                const float* __restrict__ b,
                                                float* __restrict__ xn) {
    const int idx4 = blockIdx.x * 256 + threadIdx.x;   // over float4, all 4 elems same channel
    const int base = idx4 << 2;
    const int c = base >> 12;       // /4096
    const int g = c >> 4;           // 16 channels per group
    const float mean = stats[g];
    const float rstd = stats[32 + g];
    const float scale = w[c] * rstd;
    const float shift = b[c] - mean * scale;
    float4 v = ((const float4*)x)[idx4];
    v.x = v.x * scale + shift;
    v.y = v.y * scale + shift;
    v.z = v.z * scale + shift;
    v.w = v.w * scale + shift;
    ((float4*)xn)[idx4] = v;
}

// ---------------- fp32 GEMM: C[M,N] = A[M,K] @ B[K,N] + bias[M] (+ resid)
// BM=BN=64, BK=16, 256 threads, 4x4 microtile per thread. All dims divisible.
__global__ __launch_bounds__(256) void gemm_bias(const float* __restrict__ A,
                                                 const float* __restrict__ B,
                                                 const float* __restrict__ bias,
                                                 float* __restrict__ C,
                                                 int M, int K, int N,
                                                 const float* __restrict__ resid) {
    __shared__ float As[16][64];   // As[k][m]
    __shared__ float Bs[16][64];   // Bs[k][n]
    const int tid = threadIdx.x;
    const int tx = tid & 15;        // n-dir
    const int ty = tid >> 4;        // m-dir
    const int rowBase = blockIdx.y * 64;
    const int colBase = blockIdx.x * 64;

    // A-load indices: one float4 per thread
    const int aRow = tid >> 2;
    const int a4   = (tid & 3) << 2;
    // B-load indices
    const int bRow = tid >> 4;
    const int b4   = (tid & 15) << 2;

    float acc[4][4];
#pragma unroll
    for (int i = 0; i < 4; i++)
#pragma unroll
        for (int j = 0; j < 4; j++) acc[i][j] = 0.f;

    for (int kBase = 0; kBase < K; kBase += 16) {
        __syncthreads();
        float4 av = *(const float4*)(A + (size_t)(rowBase + aRow) * K + kBase + a4);
        As[a4 + 0][aRow] = av.x;
        As[a4 + 1][aRow] = av.y;
        As[a4 + 2][aRow] = av.z;
        As[a4 + 3][aRow] = av.w;
        float4 bv = *(const float4*)(B + (size_t)(kBase + bRow) * N + colBase + b4);
        *(float4*)&Bs[bRow][b4] = bv;
        __syncthreads();
#pragma unroll
        for (int kk = 0; kk < 16; kk++) {
            float4 a = *(const float4*)&As[kk][ty << 2];
            float4 bb = *(const float4*)&Bs[kk][tx << 2];
            float ar[4] = {a.x, a.y, a.z, a.w};
            float br[4] = {bb.x, bb.y, bb.z, bb.w};
#pragma unroll
            for (int i = 0; i < 4; i++)
#pragma unroll
                for (int j = 0; j < 4; j++) acc[i][j] += ar[i] * br[j];
        }
    }

#pragma unroll
    for (int i = 0; i < 4; i++) {
        const int gr = rowBase + (ty << 2) + i;
        const int gc0 = colBase + (tx << 2);
        float bsv = bias[gr];
        float4 o;
        o.x = acc[i][0] + bsv;
        o.y = acc[i][1] + bsv;
        o.z = acc[i][2] + bsv;
        o.w = acc[i][3] + bsv;
        if (resid) {
            float4 r = *(const float4*)(resid + (size_t)gr * N + gc0);
            o.x += r.x; o.y += r.y; o.z += r.z; o.w += r.w;
        }
        *(float4*)(C + (size_t)gr * N + gc0) = o;
    }
}

// ---------------- Flash attention fp32.
// Grid: 8 heads * 256 row-tiles. Block = 256 threads = 4 waves; wave w owns rows 4w..4w+3
// of the 16-row tile. Online softmax; K/V staged as 64x64 LDS tiles.
__global__ __launch_bounds__(256) void attn_flash(const float* __restrict__ qkvp,
                                                  float* __restrict__ attno) {
    const int bid = blockIdx.x;
    const int h = bid >> 8;
    const int t0 = (bid & 255) * TB;
    const float* q = qkvp + (size_t)(h * HD) * SEQN;
    const float* k = qkvp + (size_t)(CCH + h * HD) * SEQN;
    const float* v = qkvp + (size_t)(2 * CCH + h * HD) * SEQN;

    __shared__ float qs[TB][HD];        // qs[t][d]
    __shared__ float ks[HD][SB];        // ks[d][s]  (stride 64: 2-way alias = free)
    __shared__ float vs[SB][HD + 1];    // vs[s][d]  padded (transposed scalar writes)
    __shared__ float ps[TB][SB];        // probabilities round-trip

    const int tid = threadIdx.x;
    const int wave = tid >> 6;
    const int lane = tid & 63;
    const int r0 = wave << 2;

    // stage q rows: qs[t][d] <- q[d*SEQN + t0 + t]
    for (int e = tid; e < TB * HD; e += 256) {
        int d = e >> 4;
        int t = e & 15;
        qs[t][d] = q[(size_t)d * SEQN + t0 + t];
    }

    float rowm[4], rowl[4], acc[4];
#pragma unroll
    for (int i = 0; i < 4; i++) { rowm[i] = -1e30f; rowl[i] = 0.f; acc[i] = 0.f; }

    const float scale = 0.125f;   // 64^-0.5

    for (int s0 = 0; s0 < SEQN; s0 += SB) {
        __syncthreads();
        // stage K tile (vectorized) and V tile (transposed)
        for (int e = tid; e < HD * SB / 4; e += 256) {
            int d = e >> 4;
            int s4 = (e & 15) << 2;
            float4 kv = *(const float4*)(k + (size_t)d * SEQN + s0 + s4);
            *(float4*)&ks[d][s4] = kv;
            float4 vv = *(const float4*)(v + (size_t)d * SEQN + s0 + s4);
            vs[s4 + 0][d] = vv.x;
            vs[s4 + 1][d] = vv.y;
            vs[s4 + 2][d] = vv.z;
            vs[s4 + 3][d] = vv.w;
        }
        __syncthreads();

        // QK^T: this thread computes logits (rows r0..r0+3, col s=lane)
        float dot[4] = {0.f, 0.f, 0.f, 0.f};
#pragma unroll
        for (int d = 0; d < HD; d += 4) {
            float kv[4];
#pragma unroll
            for (int j = 0; j < 4; j++) kv[j] = ks[d + j][lane];
#pragma unroll
            for (int i = 0; i < 4; i++) {
                float4 qv = *(const float4*)&qs[r0 + i][d];
                dot[i] += qv.x * kv[0] + qv.y * kv[1] + qv.z * kv[2] + qv.w * kv[3];
            }
        }
        float alpha[4];
#pragma unroll
        for (int i = 0; i < 4; i++) {
            float l = dot[i] * scale;
            float mval = l;
            for (int off = 32; off; off >>= 1) mval = fmaxf(mval, __shfl_xor(mval, off));
            float mnew = fmaxf(rowm[i], mval);
            alpha[i] = __expf(rowm[i] - mnew);
            rowm[i] = mnew;
            float p = __expf(l - mnew);
            float sv = p;
            for (int off = 32; off; off >>= 1) sv += __shfl_xor(sv, off);
            rowl[i] = rowl[i] * alpha[i] + sv;
            ps[r0 + i][lane] = p;
        }
        __syncthreads();

        // PV: this thread owns (d = lane, rows r0..r0+3)
#pragma unroll
        for (int i = 0; i < 4; i++) acc[i] *= alpha[i];
#pragma unroll 4
        for (int s = 0; s < SB; s += 4) {
            float vv[4];
#pragma unroll
            for (int j = 0; j < 4; j++) vv[j] = vs[s + j][lane];
#pragma unroll
            for (int i = 0; i < 4; i++) {
                float4 pv = *(const float4*)&ps[r0 + i][s];
                acc[i] += pv.x * vv[0] + pv.y * vv[1] + pv.z * vv[2] + pv.w * vv[3];
            }
        }
    }

    // epilogue: attno[(h*64 + d)*SEQN + t0 + r0 + i]
#pragma unroll
    for (int i = 0; i < 4; i++) {
        attno[(size_t)(h * HD + lane) * SEQN + t0 + r0 + i] = acc[i] / rowl[i];
    }
}

extern "C" void kernel_launch(void* const* d_in, const int* in_sizes, int n_in,
                              void* d_out, int out_size, void* d_ws, size_t ws_size,
                              hipStream_t stream) {
    const float* x      = (const float*)d_in[0];
    const float* gn_w   = (const float*)d_in[1];
    const float* gn_b   = (const float*)d_in[2];
    const float* qkv_w  = (const float*)d_in[3];
    const float* qkv_b  = (const float*)d_in[4];
    const float* proj_w = (const float*)d_in[5];
    const float* proj_b = (const float*)d_in[6];
    float* out = (float*)d_out;

    char* ws = (char*)d_ws;
    float* stats = (float*)ws;                           // 64 floats
    float* xn    = (float*)(ws + 256);                   // 512*4096
    float* qkv   = xn + (size_t)CCH * SEQN;              // 1536*4096
    float* attno = qkv + (size_t)3 * CCH * SEQN;         // 512*4096
    // total ws use: ~40 MB

    gn_stats<<<32, 256, 0, stream>>>(x, stats);
    gn_apply<<<(CCH * SEQN / 4) / 256, 256, 0, stream>>>(x, stats, gn_w, gn_b, xn);
    gemm_bias<<<dim3(SEQN / 64, 3 * CCH / 64), 256, 0, stream>>>(
        qkv_w, xn, qkv_b, qkv, 3 * CCH, CCH, SEQN, nullptr);
    attn_flash<<<8 * (SEQN / TB), 256, 0, stream>>>(qkv, attno);
    gemm_bias<<<dim3(SEQN / 64, CCH / 64), 256, 0, stream>>>(
        proj_w, attno, proj_b, out, CCH, CCH, SEQN, x);
}

// Round 2
// 464.599 us; speedup vs baseline: 3.1556x; 3.1556x over previous
//
#include <hip/hip_runtime.h>
#include <hip/hip_bf16.h>

#define SEQN 4096
#define HD 64
#define CCH 512
#define NH 8

typedef __attribute__((ext_vector_type(8))) short short8;   // 8 bf16 (4 VGPRs)
typedef __attribute__((ext_vector_type(4))) float f32x4;    // 4 fp32 acc

static __device__ __forceinline__ unsigned short f2bf(float f) {
    __hip_bfloat16 h = __float2bfloat16(f);
    return *(unsigned short*)&h;
}

// ---------------- GroupNorm stats: one block per group
__global__ __launch_bounds__(256) void gn_stats(const float* __restrict__ x,
                                                float* __restrict__ stats) {
    const int g = blockIdx.x;
    const float* xs = x + (size_t)g * 65536;
    const int tid = threadIdx.x;
    float s = 0.f, ss = 0.f;
    for (int i = tid; i < 65536 / 4; i += 256) {
        float4 v = ((const float4*)xs)[i];
        s  += v.x + v.y + v.z + v.w;
        ss += v.x * v.x + v.y * v.y + v.z * v.z + v.w * v.w;
    }
    for (int off = 32; off; off >>= 1) {
        s  += __shfl_xor(s, off);
        ss += __shfl_xor(ss, off);
    }
    __shared__ float red[8];
    const int wave = tid >> 6;
    const int lane = tid & 63;
    if (lane == 0) { red[wave] = s; red[4 + wave] = ss; }
    __syncthreads();
    if (tid == 0) {
        float S  = red[0] + red[1] + red[2] + red[3];
        float SS = red[4] + red[5] + red[6] + red[7];
        float mean = S * (1.f / 65536.f);
        float var  = SS * (1.f / 65536.f) - mean * mean;
        stats[g]      = mean;
        stats[32 + g] = rsqrtf(var + 1e-5f);
    }
}

// ---------------- GroupNorm apply
__global__ __launch_bounds__(256) void gn_apply(const float* __restrict__ x,
                                                const float* __restrict__ stats,
                                                const float* __restrict__ w,
                                                const float* __restrict__ b,
                                                float* __restrict__ xn) {
    const int idx4 = blockIdx.x * 256 + threadIdx.x;
    const int base = idx4 << 2;
    const int c = base >> 12;
    const int g = c >> 4;
    const float mean = stats[g];
    const float rstd = stats[32 + g];
    const float scale = w[c] * rstd;
    const float shift = b[c] - mean * scale;
    float4 v = ((const float4*)x)[idx4];
    v.x = v.x * scale + shift;
    v.y = v.y * scale + shift;
    v.z = v.z * scale + shift;
    v.w = v.w * scale + shift;
    ((float4*)xn)[idx4] = v;
}

// ---------------- fp32 GEMM (unchanged from round 1)
__global__ __launch_bounds__(256) void gemm_bias(const float* __restrict__ A,
                                                 const float* __restrict__ B,
                                                 const float* __restrict__ bias,
                                                 float* __restrict__ C,
                                                 int M, int K, int N,
                                                 const float* __restrict__ resid) {
    __shared__ float As[16][64];
    __shared__ float Bs[16][64];
    const int tid = threadIdx.x;
    const int tx = tid & 15;
    const int ty = tid >> 4;
    const int rowBase = blockIdx.y * 64;
    const int colBase = blockIdx.x * 64;

    const int aRow = tid >> 2;
    const int a4   = (tid & 3) << 2;
    const int bRow = tid >> 4;
    const int b4   = (tid & 15) << 2;

    float acc[4][4];
#pragma unroll
    for (int i = 0; i < 4; i++)
#pragma unroll
        for (int j = 0; j < 4; j++) acc[i][j] = 0.f;

    for (int kBase = 0; kBase < K; kBase += 16) {
        __syncthreads();
        float4 av = *(const float4*)(A + (size_t)(rowBase + aRow) * K + kBase + a4);
        As[a4 + 0][aRow] = av.x;
        As[a4 + 1][aRow] = av.y;
        As[a4 + 2][aRow] = av.z;
        As[a4 + 3][aRow] = av.w;
        float4 bv = *(const float4*)(B + (size_t)(kBase + bRow) * N + colBase + b4);
        *(float4*)&Bs[bRow][b4] = bv;
        __syncthreads();
#pragma unroll
        for (int kk = 0; kk < 16; kk++) {
            float4 a = *(const float4*)&As[kk][ty << 2];
            float4 bb = *(const float4*)&Bs[kk][tx << 2];
            float ar[4] = {a.x, a.y, a.z, a.w};
            float br[4] = {bb.x, bb.y, bb.z, bb.w};
#pragma unroll
            for (int i = 0; i < 4; i++)
#pragma unroll
                for (int j = 0; j < 4; j++) acc[i][j] += ar[i] * br[j];
        }
    }

#pragma unroll
    for (int i = 0; i < 4; i++) {
        const int gr = rowBase + (ty << 2) + i;
        const int gc0 = colBase + (tx << 2);
        float bsv = bias[gr];
        float4 o;
        o.x = acc[i][0] + bsv;
        o.y = acc[i][1] + bsv;
        o.z = acc[i][2] + bsv;
        o.w = acc[i][3] + bsv;
        if (resid) {
            float4 r = *(const float4*)(resid + (size_t)gr * N + gc0);
            o.x += r.x; o.y += r.y; o.z += r.z; o.w += r.w;
        }
        *(float4*)(C + (size_t)gr * N + gc0) = o;
    }
}

// ---------------- transpose+convert Q,K: qkv fp32 [c][t] -> qt/kt bf16 [h][t][d]
// z=0: Q (scale 1/8 folded in, exact in bf16); z=1: K.
__global__ __launch_bounds__(256) void qk_tcvt(const float* __restrict__ qkv,
                                               unsigned short* __restrict__ qt,
                                               unsigned short* __restrict__ kt) {
    __shared__ float tile[64][65];
    const int t0 = blockIdx.x * 64;
    const int h  = blockIdx.y;
    const int z  = blockIdx.z;
    const float* src = qkv + (size_t)(z * CCH + h * HD) * SEQN;
    unsigned short* dst = (z ? kt : qt) + (size_t)h * SEQN * HD;
    const float mul = z ? 1.0f : 0.125f;
    const int tid = threadIdx.x;
    for (int e = tid; e < 1024; e += 256) {
        int d = e >> 4;
        int t4 = (e & 15) << 2;
        float4 v = *(const float4*)(src + (size_t)d * SEQN + t0 + t4);
        tile[d][t4 + 0] = v.x;
        tile[d][t4 + 1] = v.y;
        tile[d][t4 + 2] = v.z;
        tile[d][t4 + 3] = v.w;
    }
    __syncthreads();
    for (int e = tid; e < 1024; e += 256) {
        int t = e >> 4;
        int d4 = (e & 15) << 2;
        ushort4 o;
        o.x = f2bf(tile[d4 + 0][t] * mul);
        o.y = f2bf(tile[d4 + 1][t] * mul);
        o.z = f2bf(tile[d4 + 2][t] * mul);
        o.w = f2bf(tile[d4 + 3][t] * mul);
        *(ushort4*)(dst + (size_t)(t0 + t) * HD + d4) = o;
    }
}

// ---------------- V convert (layout preserved): fp32 [c][s] -> bf16 flat
__global__ __launch_bounds__(256) void v_cvt(const float* __restrict__ v,
                                             unsigned short* __restrict__ vv) {
    const int i = blockIdx.x * 256 + threadIdx.x;
    float4 f = ((const float4*)v)[i];
    ushort4 o;
    o.x = f2bf(f.x); o.y = f2bf(f.y); o.z = f2bf(f.z); o.w = f2bf(f.w);
    ((ushort4*)vv)[i] = o;
}

// ---------------- Flash attention, bf16 MFMA.
// Grid (SEQN/64, NH); 256 threads = 4 independent waves, wave w owns 16 t-rows.
// qt/kt: [h][t|s][d] bf16 (Q pre-scaled by 1/8); vv: [h][d][s] bf16.
__global__ __launch_bounds__(256) void attn_mfma(const unsigned short* __restrict__ qt,
                                                 const unsigned short* __restrict__ kt,
                                                 const unsigned short* __restrict__ vv,
                                                 float* __restrict__ attno) {
    const int tid  = threadIdx.x;
    const int wave = tid >> 6;
    const int lane = tid & 63;
    const int quad = lane >> 4;
    const int l15  = lane & 15;
    const int h = blockIdx.y;
    const int t_base = blockIdx.x * 64 + wave * 16;

    const unsigned short* qth = qt + (size_t)h * SEQN * HD;
    const unsigned short* kth = kt + (size_t)h * SEQN * HD;
    const unsigned short* vh  = vv + (size_t)h * HD * SEQN;

    // per-wave P transpose buffer, row stride 72 bf16 (144 B, 16B-aligned rows)
    __shared__ __align__(16) unsigned short pt[4][16][72];

    // Q A-fragments: A[m=l15][k=quad*8+j], k-steps 0/1 cover d 0..31 / 32..63
    const int tq = t_base + l15;
    short8 qf0 = *(const short8*)(qth + (size_t)tq * HD + quad * 8);
    short8 qf1 = *(const short8*)(qth + (size_t)tq * HD + 32 + quad * 8);

    f32x4 oacc[4];
#pragma unroll
    for (int dt = 0; dt < 4; dt++) oacc[dt] = (f32x4){0.f, 0.f, 0.f, 0.f};
    float mrow[4] = {-1e30f, -1e30f, -1e30f, -1e30f};
    float lrow[4] = {0.f, 0.f, 0.f, 0.f};

    for (int s0 = 0; s0 < SEQN; s0 += 64) {
        // ---- K B-fragments: B[k=d][n=s], n-tiles over s (4), k-steps over d (2)
        short8 kf[4][2];
#pragma unroll
        for (int nt = 0; nt < 4; nt++) {
            const unsigned short* kp = kth + (size_t)(s0 + nt * 16 + l15) * HD + quad * 8;
            kf[nt][0] = *(const short8*)(kp);
            kf[nt][1] = *(const short8*)(kp + 32);
        }
        // ---- S = Q·K^T (pre-scaled)
        f32x4 sacc[4];
#pragma unroll
        for (int nt = 0; nt < 4; nt++) {
            f32x4 z = {0.f, 0.f, 0.f, 0.f};
            z = __builtin_amdgcn_mfma_f32_16x16x32_bf16(qf0, kf[nt][0], z, 0, 0, 0);
            sacc[nt] = __builtin_amdgcn_mfma_f32_16x16x32_bf16(qf1, kf[nt][1], z, 0, 0, 0);
        }

        // ---- online softmax. S row = quad*4+reg, col = nt*16+l15.
        float pm[4][4];
#pragma unroll
        for (int reg = 0; reg < 4; reg++) {
            float l0 = sacc[0][reg], l1 = sacc[1][reg], l2 = sacc[2][reg], l3 = sacc[3][reg];
            float mx = fmaxf(fmaxf(l0, l1), fmaxf(l2, l3));
            mx = fmaxf(mx, __shfl_xor(mx, 1));
            mx = fmaxf(mx, __shfl_xor(mx, 2));
            mx = fmaxf(mx, __shfl_xor(mx, 4));
            mx = fmaxf(mx, __shfl_xor(mx, 8));
            float mnew = fmaxf(mrow[reg], mx);
            float alpha = __expf(mrow[reg] - mnew);
            mrow[reg] = mnew;
            float p0 = __expf(l0 - mnew);
            float p1 = __expf(l1 - mnew);
            float p2 = __expf(l2 - mnew);
            float p3 = __expf(l3 - mnew);
            pm[0][reg] = p0; pm[1][reg] = p1; pm[2][reg] = p2; pm[3][reg] = p3;
            float sum = p0 + p1 + p2 + p3;
            sum += __shfl_xor(sum, 1);
            sum += __shfl_xor(sum, 2);
            sum += __shfl_xor(sum, 4);
            sum += __shfl_xor(sum, 8);
            lrow[reg] = lrow[reg] * alpha + sum;
#pragma unroll
            for (int dt = 0; dt < 4; dt++) oacc[dt][reg] *= alpha;
        }

        // ---- P: C-layout -> A-layout via per-wave LDS round-trip
        __syncthreads();   // WAR: prior iteration's reads done before overwrite
#pragma unroll
        for (int nt = 0; nt < 4; nt++)
#pragma unroll
            for (int reg = 0; reg < 4; reg++)
                pt[wave][quad * 4 + reg][nt * 16 + l15] = f2bf(pm[nt][reg]);
        __syncthreads();
        short8 pf0 = *(const short8*)&pt[wave][l15][quad * 8];
        short8 pf1 = *(const short8*)&pt[wave][l15][32 + quad * 8];

        // ---- O += P·V : B[k=s][n=d] from vv[h][d][s]
#pragma unroll
        for (int dt = 0; dt < 4; dt++) {
            const unsigned short* vp = vh + (size_t)(dt * 16 + l15) * SEQN + s0 + quad * 8;
            short8 vf0 = *(const short8*)(vp);
            short8 vf1 = *(const short8*)(vp + 32);
            oacc[dt] = __builtin_amdgcn_mfma_f32_16x16x32_bf16(pf0, vf0, oacc[dt], 0, 0, 0);
            oacc[dt] = __builtin_amdgcn_mfma_f32_16x16x32_bf16(pf1, vf1, oacc[dt], 0, 0, 0);
        }
    }

    // ---- epilogue: attno[(h*64+d)*SEQN + t] = O/l
    float inv[4];
#pragma unroll
    for (int reg = 0; reg < 4; reg++) inv[reg] = 1.0f / lrow[reg];
#pragma unroll
    for (int dt = 0; dt < 4; dt++) {
        const int d = dt * 16 + l15;
#pragma unroll
        for (int reg = 0; reg < 4; reg++) {
            const int t = t_base + quad * 4 + reg;
            attno[(size_t)(h * HD + d) * SEQN + t] = oacc[dt][reg] * inv[reg];
        }
    }
}

extern "C" void kernel_launch(void* const* d_in, const int* in_sizes, int n_in,
                              void* d_out, int out_size, void* d_ws, size_t ws_size,
                              hipStream_t stream) {
    const float* x      = (const float*)d_in[0];
    const float* gn_w   = (const float*)d_in[1];
    const float* gn_b   = (const float*)d_in[2];
    const float* qkv_w  = (const float*)d_in[3];
    const float* qkv_b  = (const float*)d_in[4];
    const float* proj_w = (const float*)d_in[5];
    const float* proj_b = (const float*)d_in[6];
    float* out = (float*)d_out;

    char* ws = (char*)d_ws;
    float* stats = (float*)ws;                            // 64 floats (256 B)
    float* xn    = (float*)(ws + 256);                    // 512*4096 f32
    float* qkv   = xn + (size_t)CCH * SEQN;               // 1536*4096 f32
    float* attno = qkv + (size_t)3 * CCH * SEQN;          // 512*4096 f32
    unsigned short* qt = (unsigned short*)(attno + (size_t)CCH * SEQN);  // 8*4096*64 bf16
    unsigned short* kt = qt + (size_t)NH * SEQN * HD;
    unsigned short* vv = kt + (size_t)NH * SEQN * HD;
    // total ws use: ~54 MB

    gn_stats<<<32, 256, 0, stream>>>(x, stats);
    gn_apply<<<(CCH * SEQN / 4) / 256, 256, 0, stream>>>(x, stats, gn_w, gn_b, xn);
    gemm_bias<<<dim3(SEQN / 64, 3 * CCH / 64), 256, 0, stream>>>(
        qkv_w, xn, qkv_b, qkv, 3 * CCH, CCH, SEQN, nullptr);
    qk_tcvt<<<dim3(SEQN / 64, NH, 2), 256, 0, stream>>>(qkv, qt, kt);
    v_cvt<<<(CCH * SEQN / 4) / 256, 256, 0, stream>>>(qkv + (size_t)2 * CCH * SEQN, vv);
    attn_mfma<<<dim3(SEQN / 64, NH), 256, 0, stream>>>(qt, kt, vv, attno);
    gemm_bias<<<dim3(SEQN / 64, CCH / 64), 256, 0, stream>>>(
        proj_w, attno, proj_b, out, CCH, CCH, SEQN, x);
}

// Round 3
// 411.011 us; speedup vs baseline: 3.5671x; 1.1304x over previous
//
#include <hip/hip_runtime.h>
#include <hip/hip_bf16.h>

#define SEQN 4096
#define HD 64
#define CCH 512
#define NH 8
#define SC 4            // s-split chunks
#define CHUNK (SEQN / SC)

typedef __attribute__((ext_vector_type(8))) short short8;   // 8 bf16 (4 VGPRs)
typedef __attribute__((ext_vector_type(4))) float f32x4;    // 4 fp32 acc

static __device__ __forceinline__ unsigned short f2bf(float f) {
    __hip_bfloat16 h = __float2bfloat16(f);
    return *(unsigned short*)&h;
}
static __device__ __forceinline__ float bf2f(unsigned short u) {
    unsigned int v = ((unsigned int)u) << 16;
    return *(float*)&v;
}

// ---------------- GroupNorm stats: one block per group
__global__ __launch_bounds__(256) void gn_stats(const float* __restrict__ x,
                                                float* __restrict__ stats) {
    const int g = blockIdx.x;
    const float* xs = x + (size_t)g * 65536;
    const int tid = threadIdx.x;
    float s = 0.f, ss = 0.f;
    for (int i = tid; i < 65536 / 4; i += 256) {
        float4 v = ((const float4*)xs)[i];
        s  += v.x + v.y + v.z + v.w;
        ss += v.x * v.x + v.y * v.y + v.z * v.z + v.w * v.w;
    }
    for (int off = 32; off; off >>= 1) {
        s  += __shfl_xor(s, off);
        ss += __shfl_xor(ss, off);
    }
    __shared__ float red[8];
    const int wave = tid >> 6;
    const int lane = tid & 63;
    if (lane == 0) { red[wave] = s; red[4 + wave] = ss; }
    __syncthreads();
    if (tid == 0) {
        float S  = red[0] + red[1] + red[2] + red[3];
        float SS = red[4] + red[5] + red[6] + red[7];
        float mean = S * (1.f / 65536.f);
        float var  = SS * (1.f / 65536.f) - mean * mean;
        stats[g]      = mean;
        stats[32 + g] = rsqrtf(var + 1e-5f);
    }
}

// ---------------- GroupNorm apply + transpose: x[c][t] f32 -> xnT[t][c] bf16
__global__ __launch_bounds__(256) void gn_norm_t(const float* __restrict__ x,
                                                 const float* __restrict__ stats,
                                                 const float* __restrict__ w,
                                                 const float* __restrict__ b,
                                                 unsigned short* __restrict__ xnT) {
    __shared__ float tile[64][65];
    const int t0 = blockIdx.x * 64;
    const int c0 = blockIdx.y * 64;
    const int tid = threadIdx.x;
    for (int e = tid; e < 1024; e += 256) {
        int r  = e >> 4;              // channel row 0..63
        int t4 = (e & 15) << 2;
        int c = c0 + r;
        int g = c >> 4;
        float mean = stats[g], rstd = stats[32 + g];
        float sc = w[c] * rstd;
        float sh = b[c] - mean * sc;
        float4 v = *(const float4*)(x + (size_t)c * SEQN + t0 + t4);
        tile[r][t4 + 0] = v.x * sc + sh;
        tile[r][t4 + 1] = v.y * sc + sh;
        tile[r][t4 + 2] = v.z * sc + sh;
        tile[r][t4 + 3] = v.w * sc + sh;
    }
    __syncthreads();
    for (int e = tid; e < 1024; e += 256) {
        int t  = e >> 4;
        int c4 = (e & 15) << 2;
        ushort4 o;
        o.x = f2bf(tile[c4 + 0][t]);
        o.y = f2bf(tile[c4 + 1][t]);
        o.z = f2bf(tile[c4 + 2][t]);
        o.w = f2bf(tile[c4 + 3][t]);
        *(ushort4*)(xnT + (size_t)(t0 + t) * CCH + c0 + c4) = o;
    }
}

// ---------------- generic f32 -> bf16 convert (flat, n4 float4 groups)
__global__ __launch_bounds__(256) void cvt_bf16(const float* __restrict__ s,
                                                unsigned short* __restrict__ d, int n4) {
    const int i = blockIdx.x * 256 + threadIdx.x;
    if (i < n4) {
        float4 f = ((const float4*)s)[i];
        ushort4 o;
        o.x = f2bf(f.x); o.y = f2bf(f.y); o.z = f2bf(f.z); o.w = f2bf(f.w);
        ((ushort4*)d)[i] = o;
    }
}

// ---------------- QKV GEMM (bf16 MFMA, direct-global fragments) with fused
// epilogue writing qt/kt [h][t][d] bf16 (Q scaled 1/8) and vv [c][t] bf16.
// A = Wb [1536][512] bf16 row-major; B = xnT [4096][512] bf16 (row = t).
__global__ __launch_bounds__(256) void gemm_qkv(const unsigned short* __restrict__ Wb,
                                                const unsigned short* __restrict__ xnT,
                                                const float* __restrict__ bias,
                                                unsigned short* __restrict__ qt,
                                                unsigned short* __restrict__ kt,
                                                unsigned short* __restrict__ vv) {
    const int tid = threadIdx.x;
    const int wave = tid >> 6;
    const int lane = tid & 63;
    const int quad = lane >> 4;
    const int l15  = lane & 15;
    const int nb = blockIdx.x;       // n-tile (t), 64 wide
    const int mb = blockIdx.y;       // m-tile (out channel), 64 wide
    const int nbase = nb * 64;
    const int mrow = mb * 64 + wave * 16 + l15;     // A-frag m
    const unsigned short* arow = Wb + (size_t)mrow * CCH;

    f32x4 acc[4];
#pragma unroll
    for (int nt = 0; nt < 4; nt++) acc[nt] = (f32x4){0.f, 0.f, 0.f, 0.f};

#pragma unroll 4
    for (int ks = 0; ks < CCH; ks += 32) {
        short8 af = *(const short8*)(arow + ks + quad * 8);
#pragma unroll
        for (int nt = 0; nt < 4; nt++) {
            short8 bf = *(const short8*)(xnT + (size_t)(nbase + nt * 16 + l15) * CCH + ks + quad * 8);
            acc[nt] = __builtin_amdgcn_mfma_f32_16x16x32_bf16(af, bf, acc[nt], 0, 0, 0);
        }
    }

    // epilogue: C row m = mb*64 + wave*16 + quad*4 + reg, col n = nbase + nt*16 + l15
    const int m0 = mb * 64 + wave * 16 + quad * 4;
    float bs[4] = {bias[m0], bias[m0 + 1], bias[m0 + 2], bias[m0 + 3]};
    const int sel = m0 >> 9;     // 0=Q, 1=K, 2=V (uniform per block)
    if (sel < 2) {
        unsigned short* dst = sel ? kt : qt;
        const float mul = sel ? 1.0f : 0.125f;
        const int h  = (m0 >> 6) & 7;
        const int d0 = m0 & 63;
#pragma unroll
        for (int nt = 0; nt < 4; nt++) {
            const int t = nbase + nt * 16 + l15;
            ushort4 o;
            o.x = f2bf((acc[nt][0] + bs[0]) * mul);
            o.y = f2bf((acc[nt][1] + bs[1]) * mul);
            o.z = f2bf((acc[nt][2] + bs[2]) * mul);
            o.w = f2bf((acc[nt][3] + bs[3]) * mul);
            *(ushort4*)(dst + ((size_t)h * SEQN + t) * HD + d0) = o;
        }
    } else {
        const int c0 = m0 - 1024;
#pragma unroll
        for (int nt = 0; nt < 4; nt++) {
            const int t = nbase + nt * 16 + l15;
#pragma unroll
            for (int reg = 0; reg < 4; reg++)
                vv[(size_t)(c0 + reg) * SEQN + t] = f2bf(acc[nt][reg] + bs[reg]);
        }
    }
}

// ---------------- proj GEMM (bf16 MFMA) + bias + residual, fp32 out.
// A = Wb [512][512] bf16; B = attnoT [4096][512] bf16.
__global__ __launch_bounds__(256) void gemm_proj(const unsigned short* __restrict__ Wb,
                                                 const unsigned short* __restrict__ attnoT,
                                                 const float* __restrict__ bias,
                                                 const float* __restrict__ resid,
                                                 float* __restrict__ out) {
    const int tid = threadIdx.x;
    const int wave = tid >> 6;
    const int lane = tid & 63;
    const int quad = lane >> 4;
    const int l15  = lane & 15;
    const int nb = blockIdx.x;
    const int mb = blockIdx.y;
    const int nbase = nb * 64;
    const int mrow = mb * 64 + wave * 16 + l15;
    const unsigned short* arow = Wb + (size_t)mrow * CCH;

    f32x4 acc[4];
#pragma unroll
    for (int nt = 0; nt < 4; nt++) acc[nt] = (f32x4){0.f, 0.f, 0.f, 0.f};

#pragma unroll 4
    for (int ks = 0; ks < CCH; ks += 32) {
        short8 af = *(const short8*)(arow + ks + quad * 8);
#pragma unroll
        for (int nt = 0; nt < 4; nt++) {
            short8 bf = *(const short8*)(attnoT + (size_t)(nbase + nt * 16 + l15) * CCH + ks + quad * 8);
            acc[nt] = __builtin_amdgcn_mfma_f32_16x16x32_bf16(af, bf, acc[nt], 0, 0, 0);
        }
    }

    const int m0 = mb * 64 + wave * 16 + quad * 4;
    float bs[4] = {bias[m0], bias[m0 + 1], bias[m0 + 2], bias[m0 + 3]};
#pragma unroll
    for (int nt = 0; nt < 4; nt++) {
        const int n = nbase + nt * 16 + l15;
#pragma unroll
        for (int reg = 0; reg < 4; reg++) {
            const size_t off = (size_t)(m0 + reg) * SEQN + n;
            out[off] = acc[nt][reg] + bs[reg] + resid[off];
        }
    }
}

// ---------------- Flash attention, S^T form, s-split.
// Grid (64 t-blocks, SC chunks, NH heads); 4 waves/block, wave owns 16 t.
// qt/kt [h][t|s][d] bf16 (Q pre-scaled); vv [c][t] (= [h][d][s]) bf16.
// Outputs per chunk: po [cb][h][t][d] bf16 (normalized), ml [cb][h][t] (m,l).
__global__ __launch_bounds__(256) void attn(const unsigned short* __restrict__ qt,
                                            const unsigned short* __restrict__ kt,
                                            const unsigned short* __restrict__ vv,
                                            unsigned short* __restrict__ po,
                                            float2* __restrict__ ml) {
    const int tid  = threadIdx.x;
    const int wave = tid >> 6;
    const int lane = tid & 63;
    const int quad = lane >> 4;
    const int l15  = lane & 15;
    const int h  = blockIdx.z;
    const int cb = blockIdx.y;
    const int t  = blockIdx.x * 64 + wave * 16 + l15;

    const unsigned short* qh = qt + (size_t)h * SEQN * HD;
    const unsigned short* kh = kt + (size_t)h * SEQN * HD;
    const unsigned short* vh = vv + (size_t)h * HD * SEQN;

    __shared__ __align__(16) unsigned short pt[4][16][72];   // [wave][t][s] = P[t][s]

    // Q B-frags (persistent): B[k=d][n=t]
    short8 qf0 = *(const short8*)(qh + (size_t)t * HD + quad * 8);
    short8 qf1 = *(const short8*)(qh + (size_t)t * HD + 32 + quad * 8);

    f32x4 oacc[4];
#pragma unroll
    for (int dt = 0; dt < 4; dt++) oacc[dt] = (f32x4){0.f, 0.f, 0.f, 0.f};
    float m = -1e30f, l = 0.f;

    const int s_beg = cb * CHUNK;
    for (int s0 = s_beg; s0 < s_beg + CHUNK; s0 += 64) {
        // ---- S^T = K·Q^T : A = K [m=s][k=d]
        f32x4 sacc[4];
#pragma unroll
        for (int nt = 0; nt < 4; nt++) {
            const unsigned short* kp = kh + (size_t)(s0 + nt * 16 + l15) * HD + quad * 8;
            short8 ka0 = *(const short8*)(kp);
            short8 ka1 = *(const short8*)(kp + 32);
            f32x4 z = (f32x4){0.f, 0.f, 0.f, 0.f};
            z = __builtin_amdgcn_mfma_f32_16x16x32_bf16(ka0, qf0, z, 0, 0, 0);
            sacc[nt] = __builtin_amdgcn_mfma_f32_16x16x32_bf16(ka1, qf1, z, 0, 0, 0);
        }
        // ---- V^T A-frags (prefetch): A[m=d][k=s] from vv[h][d][s]
        short8 va[4][2];
#pragma unroll
        for (int dt = 0; dt < 4; dt++) {
            const unsigned short* vp = vh + (size_t)(dt * 16 + l15) * SEQN + s0 + quad * 8;
            va[dt][0] = *(const short8*)(vp);
            va[dt][1] = *(const short8*)(vp + 32);
        }

        // ---- softmax: lane owns column t = l15; rows (s) spread over regs+quads
        float tm = sacc[0][0];
#pragma unroll
        for (int nt = 0; nt < 4; nt++)
#pragma unroll
            for (int reg = 0; reg < 4; reg++) tm = fmaxf(tm, sacc[nt][reg]);
        tm = fmaxf(tm, __shfl_xor(tm, 16));
        tm = fmaxf(tm, __shfl_xor(tm, 32));
        float mnew = fmaxf(m, tm);
        float alpha = __expf(m - mnew);
        m = mnew;
        float p[4][4];
        float ps = 0.f;
#pragma unroll
        for (int nt = 0; nt < 4; nt++)
#pragma unroll
            for (int reg = 0; reg < 4; reg++) {
                float e = __expf(sacc[nt][reg] - mnew);
                p[nt][reg] = e;
                ps += e;
            }
        ps += __shfl_xor(ps, 16);
        ps += __shfl_xor(ps, 32);
        l = l * alpha + ps;
#pragma unroll
        for (int dt = 0; dt < 4; dt++) {
            oacc[dt][0] *= alpha; oacc[dt][1] *= alpha;
            oacc[dt][2] *= alpha; oacc[dt][3] *= alpha;
        }

        // ---- P^T -> B-frag via per-wave LDS: pt[w][t=l15][s]
        __syncthreads();
#pragma unroll
        for (int nt = 0; nt < 4; nt++)
#pragma unroll
            for (int reg = 0; reg < 4; reg++)
                pt[wave][l15][nt * 16 + quad * 4 + reg] = f2bf(p[nt][reg]);
        __syncthreads();
        short8 pb0 = *(const short8*)&pt[wave][l15][quad * 8];
        short8 pb1 = *(const short8*)&pt[wave][l15][32 + quad * 8];

        // ---- O^T += V^T·P^T
#pragma unroll
        for (int dt = 0; dt < 4; dt++) {
            oacc[dt] = __builtin_amdgcn_mfma_f32_16x16x32_bf16(va[dt][0], pb0, oacc[dt], 0, 0, 0);
            oacc[dt] = __builtin_amdgcn_mfma_f32_16x16x32_bf16(va[dt][1], pb1, oacc[dt], 0, 0, 0);
        }
    }

    // ---- epilogue: O^T row d = dt*16+quad*4+reg, col t = l15 (lane-uniform)
    const float rl = 1.0f / l;
#pragma unroll
    for (int dt = 0; dt < 4; dt++) {
        ushort4 o;
        o.x = f2bf(oacc[dt][0] * rl);
        o.y = f2bf(oacc[dt][1] * rl);
        o.z = f2bf(oacc[dt][2] * rl);
        o.w = f2bf(oacc[dt][3] * rl);
        *(ushort4*)(po + ((size_t)(cb * NH + h) * SEQN + t) * HD + dt * 16 + quad * 4) = o;
    }
    if (quad == 0) ml[(size_t)(cb * NH + h) * SEQN + t] = make_float2(m, l);
}

// ---------------- merge s-chunks -> attnoT [t][c] bf16
__global__ __launch_bounds__(256) void attn_merge(const unsigned short* __restrict__ po,
                                                  const float2* __restrict__ ml,
                                                  unsigned short* __restrict__ attnoT) {
    const int idx = blockIdx.x * 256 + threadIdx.x;   // over 4096 t * 128 c4-groups
    const int t  = idx >> 7;
    const int c4 = (idx & 127) << 2;
    const int h  = c4 >> 6;
    const int d  = c4 & 63;

    float2 mlv[SC];
    float M = -1e30f;
#pragma unroll
    for (int cb = 0; cb < SC; cb++) {
        mlv[cb] = ml[(size_t)(cb * NH + h) * SEQN + t];
        M = fmaxf(M, mlv[cb].x);
    }
    float a0 = 0.f, a1 = 0.f, a2 = 0.f, a3 = 0.f, denom = 0.f;
#pragma unroll
    for (int cb = 0; cb < SC; cb++) {
        float wgt = __expf(mlv[cb].x - M) * mlv[cb].y;
        denom += wgt;
        ushort4 o = *(const ushort4*)(po + ((size_t)(cb * NH + h) * SEQN + t) * HD + d);
        a0 += wgt * bf2f(o.x);
        a1 += wgt * bf2f(o.y);
        a2 += wgt * bf2f(o.z);
        a3 += wgt * bf2f(o.w);
    }
    const float rd = 1.0f / denom;
    ushort4 r;
    r.x = f2bf(a0 * rd); r.y = f2bf(a1 * rd); r.z = f2bf(a2 * rd); r.w = f2bf(a3 * rd);
    *(ushort4*)(attnoT + (size_t)t * CCH + c4) = r;
}

extern "C" void kernel_launch(void* const* d_in, const int* in_sizes, int n_in,
                              void* d_out, int out_size, void* d_ws, size_t ws_size,
                              hipStream_t stream) {
    const float* x      = (const float*)d_in[0];
    const float* gn_w   = (const float*)d_in[1];
    const float* gn_b   = (const float*)d_in[2];
    const float* qkv_w  = (const float*)d_in[3];
    const float* qkv_b  = (const float*)d_in[4];
    const float* proj_w = (const float*)d_in[5];
    const float* proj_b = (const float*)d_in[6];
    float* out = (float*)d_out;

    char* ws = (char*)d_ws;
    float* stats = (float*)ws;                                     // 256 B
    unsigned short* xnT   = (unsigned short*)(ws + 256);           // 4096*512
    unsigned short* wq_bf = xnT + (size_t)SEQN * CCH;              // 1536*512
    unsigned short* wp_bf = wq_bf + (size_t)3 * CCH * CCH;         // 512*512
    unsigned short* qt    = wp_bf + (size_t)CCH * CCH;             // 8*4096*64
    unsigned short* kt    = qt + (size_t)NH * SEQN * HD;
    unsigned short* vv    = kt + (size_t)NH * SEQN * HD;
    unsigned short* po    = vv + (size_t)NH * SEQN * HD;           // SC*8*4096*64
    unsigned short* attnoT = po + (size_t)SC * NH * SEQN * HD;     // 4096*512
    float2* ml = (float2*)(attnoT + (size_t)SEQN * CCH);           // SC*8*4096
    // total ws use ~36 MB

    gn_stats<<<32, 256, 0, stream>>>(x, stats);
    gn_norm_t<<<dim3(SEQN / 64, CCH / 64), 256, 0, stream>>>(x, stats, gn_w, gn_b, xnT);
    cvt_bf16<<<(3 * CCH * CCH / 4 + 255) / 256, 256, 0, stream>>>(qkv_w, wq_bf, 3 * CCH * CCH / 4);
    cvt_bf16<<<(CCH * CCH / 4 + 255) / 256, 256, 0, stream>>>(proj_w, wp_bf, CCH * CCH / 4);
    gemm_qkv<<<dim3(SEQN / 64, 3 * CCH / 64), 256, 0, stream>>>(wq_bf, xnT, qkv_b, qt, kt, vv);
    attn<<<dim3(SEQN / 64, SC, NH), 256, 0, stream>>>(qt, kt, vv, po, ml);
    attn_merge<<<SEQN * 128 / 256, 256, 0, stream>>>(po, ml, attnoT);
    gemm_proj<<<dim3(SEQN / 64, CCH / 64), 256, 0, stream>>>(wp_bf, attnoT, proj_b, x, out);
}

// Round 4
// 259.225 us; speedup vs baseline: 5.6557x; 1.5855x over previous
//
#include <hip/hip_runtime.h>
#include <hip/hip_bf16.h>

#define SEQN 4096
#define HD 64
#define CCH 512
#define NH 8
#define SC 4            // s-split chunks
#define CHUNK (SEQN / SC)

typedef __attribute__((ext_vector_type(8))) short short8;   // 8 bf16 (4 VGPRs)
typedef __attribute__((ext_vector_type(4))) float f32x4;    // 4 fp32 acc

#define AS1 __attribute__((address_space(1)))
#define AS3 __attribute__((address_space(3)))

static __device__ __forceinline__ unsigned short f2bf(float f) {
    __hip_bfloat16 h = __float2bfloat16(f);
    return *(unsigned short*)&h;
}
static __device__ __forceinline__ float bf2f(unsigned short u) {
    unsigned int v = ((unsigned int)u) << 16;
    return *(float*)&v;
}
static __device__ __forceinline__ void load_lds_16(const unsigned short* g, unsigned short* l) {
    __builtin_amdgcn_global_load_lds((const AS1 void*)g, (AS3 void*)l, 16, 0, 0);
}

// ---------------- GroupNorm stats: one block per group
__global__ __launch_bounds__(256) void gn_stats(const float* __restrict__ x,
                                                float* __restrict__ stats) {
    const int g = blockIdx.x;
    const float* xs = x + (size_t)g * 65536;
    const int tid = threadIdx.x;
    float s = 0.f, ss = 0.f;
    for (int i = tid; i < 65536 / 4; i += 256) {
        float4 v = ((const float4*)xs)[i];
        s  += v.x + v.y + v.z + v.w;
        ss += v.x * v.x + v.y * v.y + v.z * v.z + v.w * v.w;
    }
    for (int off = 32; off; off >>= 1) {
        s  += __shfl_xor(s, off);
        ss += __shfl_xor(ss, off);
    }
    __shared__ float red[8];
    const int wave = tid >> 6;
    const int lane = tid & 63;
    if (lane == 0) { red[wave] = s; red[4 + wave] = ss; }
    __syncthreads();
    if (tid == 0) {
        float S  = red[0] + red[1] + red[2] + red[3];
        float SS = red[4] + red[5] + red[6] + red[7];
        float mean = S * (1.f / 65536.f);
        float var  = SS * (1.f / 65536.f) - mean * mean;
        stats[g]      = mean;
        stats[32 + g] = rsqrtf(var + 1e-5f);
    }
}

// ---------------- GroupNorm apply + transpose: x[c][t] f32 -> xnT[t][c] bf16
__global__ __launch_bounds__(256) void gn_norm_t(const float* __restrict__ x,
                                                 const float* __restrict__ stats,
                                                 const float* __restrict__ w,
                                                 const float* __restrict__ b,
                                                 unsigned short* __restrict__ xnT) {
    __shared__ float tile[64][65];
    const int t0 = blockIdx.x * 64;
    const int c0 = blockIdx.y * 64;
    const int tid = threadIdx.x;
    for (int e = tid; e < 1024; e += 256) {
        int r  = e >> 4;              // channel row 0..63
        int t4 = (e & 15) << 2;
        int c = c0 + r;
        int g = c >> 4;
        float mean = stats[g], rstd = stats[32 + g];
        float sc = w[c] * rstd;
        float sh = b[c] - mean * sc;
        float4 v = *(const float4*)(x + (size_t)c * SEQN + t0 + t4);
        tile[r][t4 + 0] = v.x * sc + sh;
        tile[r][t4 + 1] = v.y * sc + sh;
        tile[r][t4 + 2] = v.z * sc + sh;
        tile[r][t4 + 3] = v.w * sc + sh;
    }
    __syncthreads();
    for (int e = tid; e < 1024; e += 256) {
        int t  = e >> 4;
        int c4 = (e & 15) << 2;
        ushort4 o;
        o.x = f2bf(tile[c4 + 0][t]);
        o.y = f2bf(tile[c4 + 1][t]);
        o.z = f2bf(tile[c4 + 2][t]);
        o.w = f2bf(tile[c4 + 3][t]);
        *(ushort4*)(xnT + (size_t)(t0 + t) * CCH + c0 + c4) = o;
    }
}

// ---------------- generic f32 -> bf16 convert (flat, n4 float4 groups)
__global__ __launch_bounds__(256) void cvt_bf16(const float* __restrict__ s,
                                                unsigned short* __restrict__ d, int n4) {
    const int i = blockIdx.x * 256 + threadIdx.x;
    if (i < n4) {
        float4 f = ((const float4*)s)[i];
        ushort4 o;
        o.x = f2bf(f.x); o.y = f2bf(f.y); o.z = f2bf(f.z); o.w = f2bf(f.w);
        ((ushort4*)d)[i] = o;
    }
}

// ---------------- QKV GEMM (bf16 MFMA, direct-global fragments) with fused
// epilogue writing qt/kt [h][t][d] bf16 (Q scaled 1/8) and vv [c][t] bf16.
__global__ __launch_bounds__(256) void gemm_qkv(const unsigned short* __restrict__ Wb,
                                                const unsigned short* __restrict__ xnT,
                                                const float* __restrict__ bias,
                                                unsigned short* __restrict__ qt,
                                                unsigned short* __restrict__ kt,
                                                unsigned short* __restrict__ vv) {
    const int tid = threadIdx.x;
    const int wave = tid >> 6;
    const int lane = tid & 63;
    const int quad = lane >> 4;
    const int l15  = lane & 15;
    const int nb = blockIdx.x;       // n-tile (t), 64 wide
    const int mb = blockIdx.y;       // m-tile (out channel), 64 wide
    const int nbase = nb * 64;
    const int mrow = mb * 64 + wave * 16 + l15;     // A-frag m
    const unsigned short* arow = Wb + (size_t)mrow * CCH;

    f32x4 acc[4];
#pragma unroll
    for (int nt = 0; nt < 4; nt++) acc[nt] = (f32x4){0.f, 0.f, 0.f, 0.f};

#pragma unroll 4
    for (int ks = 0; ks < CCH; ks += 32) {
        short8 af = *(const short8*)(arow + ks + quad * 8);
#pragma unroll
        for (int nt = 0; nt < 4; nt++) {
            short8 bf = *(const short8*)(xnT + (size_t)(nbase + nt * 16 + l15) * CCH + ks + quad * 8);
            acc[nt] = __builtin_amdgcn_mfma_f32_16x16x32_bf16(af, bf, acc[nt], 0, 0, 0);
        }
    }

    const int m0 = mb * 64 + wave * 16 + quad * 4;
    float bs[4] = {bias[m0], bias[m0 + 1], bias[m0 + 2], bias[m0 + 3]};
    const int sel = m0 >> 9;     // 0=Q, 1=K, 2=V (uniform per block)
    if (sel < 2) {
        unsigned short* dst = sel ? kt : qt;
        const float mul = sel ? 1.0f : 0.125f;
        const int h  = (m0 >> 6) & 7;
        const int d0 = m0 & 63;
#pragma unroll
        for (int nt = 0; nt < 4; nt++) {
            const int t = nbase + nt * 16 + l15;
            ushort4 o;
            o.x = f2bf((acc[nt][0] + bs[0]) * mul);
            o.y = f2bf((acc[nt][1] + bs[1]) * mul);
            o.z = f2bf((acc[nt][2] + bs[2]) * mul);
            o.w = f2bf((acc[nt][3] + bs[3]) * mul);
            *(ushort4*)(dst + ((size_t)h * SEQN + t) * HD + d0) = o;
        }
    } else {
        const int c0 = m0 - 1024;
#pragma unroll
        for (int nt = 0; nt < 4; nt++) {
            const int t = nbase + nt * 16 + l15;
#pragma unroll
            for (int reg = 0; reg < 4; reg++)
                vv[(size_t)(c0 + reg) * SEQN + t] = f2bf(acc[nt][reg] + bs[reg]);
        }
    }
}

// ---------------- proj GEMM (bf16 MFMA) + bias + residual, fp32 out.
__global__ __launch_bounds__(256) void gemm_proj(const unsigned short* __restrict__ Wb,
                                                 const unsigned short* __restrict__ attnoT,
                                                 const float* __restrict__ bias,
                                                 const float* __restrict__ resid,
                                                 float* __restrict__ out) {
    const int tid = threadIdx.x;
    const int wave = tid >> 6;
    const int lane = tid & 63;
    const int quad = lane >> 4;
    const int l15  = lane & 15;
    const int nb = blockIdx.x;
    const int mb = blockIdx.y;
    const int nbase = nb * 64;
    const int mrow = mb * 64 + wave * 16 + l15;
    const unsigned short* arow = Wb + (size_t)mrow * CCH;

    f32x4 acc[4];
#pragma unroll
    for (int nt = 0; nt < 4; nt++) acc[nt] = (f32x4){0.f, 0.f, 0.f, 0.f};

#pragma unroll 4
    for (int ks = 0; ks < CCH; ks += 32) {
        short8 af = *(const short8*)(arow + ks + quad * 8);
#pragma unroll
        for (int nt = 0; nt < 4; nt++) {
            short8 bf = *(const short8*)(attnoT + (size_t)(nbase + nt * 16 + l15) * CCH + ks + quad * 8);
            acc[nt] = __builtin_amdgcn_mfma_f32_16x16x32_bf16(af, bf, acc[nt], 0, 0, 0);
        }
    }

    const int m0 = mb * 64 + wave * 16 + quad * 4;
    float bs[4] = {bias[m0], bias[m0 + 1], bias[m0 + 2], bias[m0 + 3]};
#pragma unroll
    for (int nt = 0; nt < 4; nt++) {
        const int n = nbase + nt * 16 + l15;
#pragma unroll
        for (int reg = 0; reg < 4; reg++) {
            const size_t off = (size_t)(m0 + reg) * SEQN + n;
            out[off] = acc[nt][reg] + bs[reg] + resid[off];
        }
    }
}

// ---------------- Flash attention, S^T form, s-split, LDS-staged K/V with
// double buffer + XOR swizzle. 4 waves/block, wave owns 16 t; one barrier/iter.
// qt/kt [h][t|s][d] bf16 (Q pre-scaled); vv [h][d][s] bf16.
__global__ __launch_bounds__(256) void attn(const unsigned short* __restrict__ qt,
                                            const unsigned short* __restrict__ kt,
                                            const unsigned short* __restrict__ vv,
                                            unsigned short* __restrict__ po,
                                            float2* __restrict__ ml) {
    const int tid  = threadIdx.x;
    const int wave = tid >> 6;
    const int lane = tid & 63;
    const int quad = lane >> 4;
    const int l15  = lane & 15;
    const int h  = blockIdx.z;
    const int cb = blockIdx.y;
    const int t  = blockIdx.x * 64 + wave * 16 + l15;

    const unsigned short* qh = qt + (size_t)h * SEQN * HD;
    const unsigned short* kh = kt + (size_t)h * SEQN * HD;
    const unsigned short* vh = vv + (size_t)h * HD * SEQN;

    // swizzled K/V tiles: element (row r, col8 slot) at r*64 + slot*8, where
    // slot = (col>>3) ^ (r&7). K rows = s (d-minor); V rows = d (s-minor).
    __shared__ __align__(16) unsigned short ksm[2][4096];
    __shared__ __align__(16) unsigned short vsm[2][4096];
    __shared__ __align__(16) unsigned short pt[4][16][72];   // per-wave P^T

    const int sl   = lane >> 3;          // sub-row within 8-row chunk
    const int slot = lane & 7;           // 16B slot within row
    const int src8 = (slot ^ sl) * 8;    // swizzled source col8*8 (r&7 == sl)

    // Q B-frags (persistent): B[k=d][n=t]
    short8 qf0 = *(const short8*)(qh + (size_t)t * HD + quad * 8);
    short8 qf1 = *(const short8*)(qh + (size_t)t * HD + 32 + quad * 8);

    f32x4 oacc[4];
#pragma unroll
    for (int dt = 0; dt < 4; dt++) oacc[dt] = (f32x4){0.f, 0.f, 0.f, 0.f};
    float m = -1e30f, l = 0.f;

    const int s_beg = cb * CHUNK;
    const int NIT = CHUNK / 64;

    // stage tile into buffer buf: per wave 2 K-chunks + 2 V-chunks (1 KB each)
    auto stage = [&](int buf, int s0) {
#pragma unroll
        for (int r = 0; r < 2; r++) {
            const int c = r * 4 + wave;          // chunk 0..7 (8 rows each)
            const int row = c * 8 + sl;
            load_lds_16(kh + (size_t)(s0 + row) * HD + src8, &ksm[buf][c * 512 ]);
            load_lds_16(vh + (size_t)row * SEQN + s0 + src8, &vsm[buf][c * 512]);
        }
    };

    stage(0, s_beg);

    for (int it = 0; it < NIT; it++) {
        const int s0 = s_beg + it * 64;
        const int cur = it & 1;
        __syncthreads();   // drains current buffer's staging; WAR for next stage
        if (it + 1 < NIT) stage(cur ^ 1, s0 + 64);

        const unsigned short* ks = ksm[cur];
        const unsigned short* vs = vsm[cur];

        // ---- S^T = K·Q^T : A = K [m=s][k=d], frags from swizzled LDS
        f32x4 sacc[4];
#pragma unroll
        for (int nt = 0; nt < 4; nt++) {
            const int r = nt * 16 + l15;
            short8 ka0 = *(const short8*)(ks + r * 64 + ((quad    ) ^ (l15 & 7)) * 8);
            short8 ka1 = *(const short8*)(ks + r * 64 + ((quad + 4) ^ (l15 & 7)) * 8);
            f32x4 z = (f32x4){0.f, 0.f, 0.f, 0.f};
            z = __builtin_amdgcn_mfma_f32_16x16x32_bf16(ka0, qf0, z, 0, 0, 0);
            sacc[nt] = __builtin_amdgcn_mfma_f32_16x16x32_bf16(ka1, qf1, z, 0, 0, 0);
        }

        // ---- softmax: lane owns column t; rows (s) spread over regs+quads
        float tm = sacc[0][0];
#pragma unroll
        for (int nt = 0; nt < 4; nt++)
#pragma unroll
            for (int reg = 0; reg < 4; reg++) tm = fmaxf(tm, sacc[nt][reg]);
        tm = fmaxf(tm, __shfl_xor(tm, 16));
        tm = fmaxf(tm, __shfl_xor(tm, 32));
        float mnew = fmaxf(m, tm);
        float alpha = __expf(m - mnew);
        m = mnew;
        float p[4][4];
        float ps = 0.f;
#pragma unroll
        for (int nt = 0; nt < 4; nt++)
#pragma unroll
            for (int reg = 0; reg < 4; reg++) {
                float e = __expf(sacc[nt][reg] - mnew);
                p[nt][reg] = e;
                ps += e;
            }
        ps += __shfl_xor(ps, 16);
        ps += __shfl_xor(ps, 32);
        l = l * alpha + ps;
#pragma unroll
        for (int dt = 0; dt < 4; dt++) {
            oacc[dt][0] *= alpha; oacc[dt][1] *= alpha;
            oacc[dt][2] *= alpha; oacc[dt][3] *= alpha;
        }

        // ---- P^T -> B-frag via per-wave LDS (no block barrier needed)
#pragma unroll
        for (int nt = 0; nt < 4; nt++) {
            unsigned int w01 = (unsigned int)f2bf(p[nt][0]) | ((unsigned int)f2bf(p[nt][1]) << 16);
            unsigned int w23 = (unsigned int)f2bf(p[nt][2]) | ((unsigned int)f2bf(p[nt][3]) << 16);
            *(unsigned int*)&pt[wave][l15][nt * 16 + quad * 4]     = w01;
            *(unsigned int*)&pt[wave][l15][nt * 16 + quad * 4 + 2] = w23;
        }
        short8 pb0 = *(const short8*)&pt[wave][l15][quad * 8];
        short8 pb1 = *(const short8*)&pt[wave][l15][32 + quad * 8];

        // ---- O^T += V^T·P^T : A = V^T [m=d][k=s] from swizzled LDS
#pragma unroll
        for (int dt = 0; dt < 4; dt++) {
            const int r = dt * 16 + l15;
            short8 va0 = *(const short8*)(vs + r * 64 + ((quad    ) ^ (l15 & 7)) * 8);
            short8 va1 = *(const short8*)(vs + r * 64 + ((quad + 4) ^ (l15 & 7)) * 8);
            oacc[dt] = __builtin_amdgcn_mfma_f32_16x16x32_bf16(va0, pb0, oacc[dt], 0, 0, 0);
            oacc[dt] = __builtin_amdgcn_mfma_f32_16x16x32_bf16(va1, pb1, oacc[dt], 0, 0, 0);
        }
    }

    // ---- epilogue: O^T row d = dt*16+quad*4+reg, col t = l15 (lane-uniform)
    const float rl = 1.0f / l;
#pragma unroll
    for (int dt = 0; dt < 4; dt++) {
        ushort4 o;
        o.x = f2bf(oacc[dt][0] * rl);
        o.y = f2bf(oacc[dt][1] * rl);
        o.z = f2bf(oacc[dt][2] * rl);
        o.w = f2bf(oacc[dt][3] * rl);
        *(ushort4*)(po + ((size_t)(cb * NH + h) * SEQN + t) * HD + dt * 16 + quad * 4) = o;
    }
    if (quad == 0) ml[(size_t)(cb * NH + h) * SEQN + t] = make_float2(m, l);
}

// ---------------- merge s-chunks -> attnoT [t][c] bf16
__global__ __launch_bounds__(256) void attn_merge(const unsigned short* __restrict__ po,
                                                  const float2* __restrict__ ml,
                                                  unsigned short* __restrict__ attnoT) {
    const int idx = blockIdx.x * 256 + threadIdx.x;
    const int t  = idx >> 7;
    const int c4 = (idx & 127) << 2;
    const int h  = c4 >> 6;
    const int d  = c4 & 63;

    float2 mlv[SC];
    float M = -1e30f;
#pragma unroll
    for (int cb = 0; cb < SC; cb++) {
        mlv[cb] = ml[(size_t)(cb * NH + h) * SEQN + t];
        M = fmaxf(M, mlv[cb].x);
    }
    float a0 = 0.f, a1 = 0.f, a2 = 0.f, a3 = 0.f, denom = 0.f;
#pragma unroll
    for (int cb = 0; cb < SC; cb++) {
        float wgt = __expf(mlv[cb].x - M) * mlv[cb].y;
        denom += wgt;
        ushort4 o = *(const ushort4*)(po + ((size_t)(cb * NH + h) * SEQN + t) * HD + d);
        a0 += wgt * bf2f(o.x);
        a1 += wgt * bf2f(o.y);
        a2 += wgt * bf2f(o.z);
        a3 += wgt * bf2f(o.w);
    }
    const float rd = 1.0f / denom;
    ushort4 r;
    r.x = f2bf(a0 * rd); r.y = f2bf(a1 * rd); r.z = f2bf(a2 * rd); r.w = f2bf(a3 * rd);
    *(ushort4*)(attnoT + (size_t)t * CCH + c4) = r;
}

extern "C" void kernel_launch(void* const* d_in, const int* in_sizes, int n_in,
                              void* d_out, int out_size, void* d_ws, size_t ws_size,
                              hipStream_t stream) {
    const float* x      = (const float*)d_in[0];
    const float* gn_w   = (const float*)d_in[1];
    const float* gn_b   = (const float*)d_in[2];
    const float* qkv_w  = (const float*)d_in[3];
    const float* qkv_b  = (const float*)d_in[4];
    const float* proj_w = (const float*)d_in[5];
    const float* proj_b = (const float*)d_in[6];
    float* out = (float*)d_out;

    char* ws = (char*)d_ws;
    float* stats = (float*)ws;                                     // 256 B
    unsigned short* xnT   = (unsigned short*)(ws + 256);           // 4096*512
    unsigned short* wq_bf = xnT + (size_t)SEQN * CCH;              // 1536*512
    unsigned short* wp_bf = wq_bf + (size_t)3 * CCH * CCH;         // 512*512
    unsigned short* qt    = wp_bf + (size_t)CCH * CCH;             // 8*4096*64
    unsigned short* kt    = qt + (size_t)NH * SEQN * HD;
    unsigned short* vv    = kt + (size_t)NH * SEQN * HD;
    unsigned short* po    = vv + (size_t)NH * SEQN * HD;           // SC*8*4096*64
    unsigned short* attnoT = po + (size_t)SC * NH * SEQN * HD;     // 4096*512
    float2* ml = (float2*)(attnoT + (size_t)SEQN * CCH);           // SC*8*4096

    gn_stats<<<32, 256, 0, stream>>>(x, stats);
    gn_norm_t<<<dim3(SEQN / 64, CCH / 64), 256, 0, stream>>>(x, stats, gn_w, gn_b, xnT);
    cvt_bf16<<<(3 * CCH * CCH / 4 + 255) / 256, 256, 0, stream>>>(qkv_w, wq_bf, 3 * CCH * CCH / 4);
    cvt_bf16<<<(CCH * CCH / 4 + 255) / 256, 256, 0, stream>>>(proj_w, wp_bf, CCH * CCH / 4);
    gemm_qkv<<<dim3(SEQN / 64, 3 * CCH / 64), 256, 0, stream>>>(wq_bf, xnT, qkv_b, qt, kt, vv);
    attn<<<dim3(SEQN / 64, SC, NH), 256, 0, stream>>>(qt, kt, vv, po, ml);
    attn_merge<<<SEQN * 128 / 256, 256, 0, stream>>>(po, ml, attnoT);
    gemm_proj<<<dim3(SEQN / 64, CCH / 64), 256, 0, stream>>>(wp_bf, attnoT, proj_b, x, out);
}